// Round 8
// baseline (122.151 us; speedup 1.0000x reference)
//
#include <hip/hip_runtime.h>

#define Bsz 4
#define Cch 64
#define Hh 128
#define Ww 128
#define NOFF 18      // 2*3*3 offset channels
#define CK 576       // 64*9 reduction length for deform einsum (K = k*64 + c)
#define CKPAD 580    // smp row stride (bf16): 1160B -> conflict-free r/w patterns

typedef __attribute__((ext_vector_type(8))) short short8;
typedef __attribute__((ext_vector_type(4))) float floatx4;

__device__ __forceinline__ unsigned short f2bf(float f) {
    union { float f; unsigned u; } v; v.f = f;
    unsigned r = v.u + 0x7fff + ((v.u >> 16) & 1);   // round-to-nearest-even
    return (unsigned short)(r >> 16);
}
__device__ __forceinline__ float bflo(unsigned d) {
    union { unsigned u; float f; } v; v.u = d << 16; return v.f;
}
__device__ __forceinline__ float bfhi(unsigned d) {
    union { unsigned u; float f; } v; v.u = d & 0xffff0000u; return v.f;
}

// ---------------------------------------------------------------------------
// Kernel A1: deform weight w[oc][c][tap] f32 -> wbf[oc][tap*64 + c] bf16
__global__ __launch_bounds__(256) void convert_w(const float* __restrict__ w,
                                                 unsigned short* __restrict__ wbf) {
    int t = blockIdx.x * 256 + threadIdx.x;
    if (t >= Cch * CK) return;
    int oc = t / CK;
    int rem = t % CK;
    int k = rem >> 6;
    int c = rem & 63;
    wbf[t] = f2bf(w[(oc * Cch + c) * 9 + k]);
}

// Kernel A2: offset weight wo[oc][ci][tap] -> w9[tap][32 oc (pad)][128 ci] bf16
__global__ __launch_bounds__(256) void convert_w9(const float* __restrict__ wo,
                                                  unsigned short* __restrict__ w9) {
    int t = blockIdx.x * 256 + threadIdx.x;
    if (t >= 9 * 32 * 128) return;
    int ci = t & 127;
    int ocp = (t >> 7) & 31;
    int tap = t >> 12;
    w9[t] = (ocp < NOFF) ? f2bf(wo[(ocp * 128 + ci) * 9 + tap]) : (unsigned short)0;
}

// Kernel A3: transpose x[b][c][h][w] f32 -> xtr[b][h*w][64 c] bf16 (channel-minor)
__global__ __launch_bounds__(256) void transpose_x(const float* __restrict__ x,
                                                   unsigned short* __restrict__ xtr) {
    __shared__ unsigned short tile[64][66];
    int blk = blockIdx.x;
    int b = blk >> 8;
    int hw0 = (blk & 255) << 6;
    int tid = threadIdx.x;
    int px = tid & 63, cg = tid >> 6;
    const float* src = x + ((size_t)b << 20) + hw0 + px;
#pragma unroll
    for (int i = 0; i < 16; ++i) {
        int c = cg * 16 + i;
        tile[px][c] = f2bf(src[(size_t)c << 14]);
    }
    __syncthreads();
    int p2 = tid >> 4, cq = tid & 15;
#pragma unroll
    for (int j = 0; j < 4; ++j) {
        int px2 = j * 16 + p2;
        uint2 v = make_uint2(
            (unsigned)tile[px2][cq * 4 + 0] | ((unsigned)tile[px2][cq * 4 + 1] << 16),
            (unsigned)tile[px2][cq * 4 + 2] | ((unsigned)tile[px2][cq * 4 + 3] << 16));
        *(uint2*)(xtr + ((size_t)b << 20) + ((size_t)(hw0 + px2) << 6) + cq * 4) = v;
    }
}

// ---------------------------------------------------------------------------
// Kernel A: offset conv as 9 tap-shifted MFMA GEMMs. Block = (b, h, 16-px strip).
// A-fragments preloaded to registers at entry (overlaps phase-1 staging).
__global__ __launch_bounds__(256, 4) void offset_mfma(const float* __restrict__ x,
                                                      const float* __restrict__ ref,
                                                      const unsigned short* __restrict__ w9,
                                                      const float* __restrict__ bias,
                                                      float* __restrict__ offs) {
    __shared__ unsigned short tile[3 * 18 * 128];   // 13.5 KB
    __shared__ float red[2][64][4];                 // 2 KB

    int bi = blockIdx.x;
    int b = bi >> 10;
    int rem = bi & 1023;
    int h = rem >> 3;
    int w0 = (rem & 7) << 4;
    int tid = threadIdx.x;

    int wv = tid >> 6, lane = tid & 63;
    int to = wv & 1;          // oc tile: base = to*16
    int kh = wv >> 1;         // ci half: base = kh*64 (0: x, 1: ref)
    int r16 = lane & 15;      // A row (oc) / B col (px)
    int g = lane >> 4;        // k-group

    // Preload all 18 A fragments (issued before staging loads; L2-broadcast)
    short8 a9[18];
#pragma unroll
    for (int tap = 0; tap < 9; ++tap) {
        const unsigned short* arow =
            w9 + ((size_t)(tap * 32 + to * 16 + r16) << 7) + kh * 64 + g * 8;
        a9[tap * 2 + 0] = *(const short8*)(arow);
        a9[tap * 2 + 1] = *(const short8*)(arow + 32);
    }

#pragma unroll
    for (int it = 0; it < 7; ++it) {
        int idx = it * 256 + tid;
        if (idx < 1728) {
            int xx = idx % 18;
            int rest = idx / 18;
            int row = rest % 3;
            int ciq = rest / 3;
            int ci0 = ciq << 2;
            int yy = h + row - 1;
            int xg = w0 + xx - 1;
            const float* src = (ci0 < Cch)
                ? (x + ((size_t)(b * Cch + ci0) << 14))
                : (ref + ((size_t)(b * Cch + ci0 - Cch) << 14));
            float v0 = 0.f, v1 = 0.f, v2 = 0.f, v3 = 0.f;
            if ((unsigned)yy < (unsigned)Hh && (unsigned)xg < (unsigned)Ww) {
                const float* p = src + (yy << 7) + xg;
                v0 = p[0]; v1 = p[1 << 14]; v2 = p[2 << 14]; v3 = p[3 << 14];
            }
            unsigned lo = (unsigned)f2bf(v0) | ((unsigned)f2bf(v1) << 16);
            unsigned hi = (unsigned)f2bf(v2) | ((unsigned)f2bf(v3) << 16);
            int slot = (row * 18 + xx) * 128 + (ci0 ^ ((xx & 7) << 3));
            *(uint2*)(&tile[slot]) = make_uint2(lo, hi);
        }
    }
    __syncthreads();

    floatx4 acc = {0.f, 0.f, 0.f, 0.f};
#pragma unroll
    for (int tap = 0; tap < 9; ++tap) {
        int dy = tap / 3, dx = tap % 3;
        int xxr = r16 + dx;                              // 0..17
        const unsigned short* brow = &tile[(dy * 18 + xxr) * 128];
        int sw = (xxr & 7) << 3;
#pragma unroll
        for (int kk = 0; kk < 2; ++kk) {
            int cb = kh * 64 + kk * 32 + g * 8;
            short8 bb = *(const short8*)(brow + (cb ^ sw));
            acc = __builtin_amdgcn_mfma_f32_16x16x32_bf16(a9[tap * 2 + kk], bb, acc, 0, 0, 0);
        }
    }

    if (kh == 1) {
#pragma unroll
        for (int r = 0; r < 4; ++r) red[to][lane][r] = acc[r];
    }
    __syncthreads();
    if (kh == 0) {
#pragma unroll
        for (int r = 0; r < 4; ++r) {
            int oc = to * 16 + g * 4 + r;
            if (oc >= NOFF) break;
            float v = acc[r] + red[to][lane][r] + bias[oc];
            v = fminf(fmaxf(v, -10.0f), 10.0f);
            offs[(size_t)((b * Hh + h) * Ww + w0 + r16) * NOFF + oc] = v;
        }
    }
}

// ---------------------------------------------------------------------------
// Kernel B: deformable conv with MFMA einsum, sampling from channel-minor xtr.
// Coords computed per-thread in registers (no LDS meta, no barrier #1);
// A-fragments preloaded at entry; single barrier before the MFMA phase.
__global__ __launch_bounds__(256, 4) void deform_mfma(const unsigned short* __restrict__ xtr,
                                                      const unsigned short* __restrict__ wbf,
                                                      const float* __restrict__ offs,
                                                      float* __restrict__ out) {
    __shared__ unsigned short smp[16][CKPAD];   // [px][k*64+c] bf16

    int bi = blockIdx.x;
    int b = bi >> 10;
    int rem = bi & 1023;
    int h = rem >> 3;
    int w0 = (rem & 7) << 4;
    int tid = threadIdx.x;

    int wv = tid >> 6, lane = tid & 63;
    int r16 = lane & 15;          // A row (=o sub-index) and B col (=px)
    int g = lane >> 4;            // k-group

    // Preload all 18 A fragments (same 72KB for every block -> L2 broadcast)
    short8 a[18];
    const short8* ap = (const short8*)(wbf + (size_t)(wv * 16 + r16) * CK + g * 8);
#pragma unroll
    for (int kk = 0; kk < 18; ++kk) a[kk] = ap[kk * 4];

    int p = tid >> 4;          // pixel (16 lanes share -> broadcast offs reads)
    int cq = tid & 15;         // channel quad
    const float2* op2 = (const float2*)(offs + (size_t)((b * Hh + h) * Ww + w0 + p) * NOFF);
    const char* xb = (const char*)xtr + ((size_t)b << 21) + cq * 8;

#pragma unroll
    for (int k = 0; k < 9; ++k) {
        int ky = k / 3, kx = k % 3;
        float2 o = op2[k];
        float ys = (float)(h - 1 + ky) + o.x;
        float xs = (float)(w0 + p - 1 + kx) + o.y;
        float fy = floorf(ys), fx = floorf(xs);
        int iy0 = (int)fy, ix0 = (int)fx;
        float ty = ys - fy, tx = xs - fx;
        float wy0 = (1.f - ty) * (((unsigned)iy0 < (unsigned)Hh) ? 1.f : 0.f);
        float wy1 = ty         * (((unsigned)(iy0 + 1) < (unsigned)Hh) ? 1.f : 0.f);
        float wx0 = (1.f - tx) * (((unsigned)ix0 < (unsigned)Ww) ? 1.f : 0.f);
        float wx1 = tx         * (((unsigned)(ix0 + 1) < (unsigned)Ww) ? 1.f : 0.f);
        int ixb  = min(max(ix0, 0), Ww - 2);          // pair base: [ixb, ixb+1]
        int iy0c = min(max(iy0, 0), Hh - 1);
        int iy1c = min(max(iy0 + 1, 0), Hh - 1);
        bool sw0 = (min(max(ix0, 0), Ww - 1) != ixb);
        bool sw1 = (min(max(ix0 + 1, 0), Ww - 1) != ixb);
        float w00 = wy0 * wx0, w01 = wy0 * wx1, w10 = wy1 * wx0, w11 = wy1 * wx1;
        float A  = (sw0 ? 0.f : w00) + (sw1 ? 0.f : w01);   // (y0, ixb)
        float Bw = (sw0 ? w00 : 0.f) + (sw1 ? w01 : 0.f);   // (y0, ixb+1)
        float Cw = (sw0 ? 0.f : w10) + (sw1 ? 0.f : w11);   // (y1, ixb)
        float Dw = (sw0 ? w10 : 0.f) + (sw1 ? w11 : 0.f);   // (y1, ixb+1)
        int m0 = ((iy0c << 7) + ixb) << 7;   // position byte offsets (64ch * 2B)
        int m1 = ((iy1c << 7) + ixb) << 7;
        uint2 q00 = *(const uint2*)(xb + m0);
        uint2 q01 = *(const uint2*)(xb + m0 + 128);
        uint2 q10 = *(const uint2*)(xb + m1);
        uint2 q11 = *(const uint2*)(xb + m1 + 128);
        float s0 = bflo(q00.x) * A + bflo(q01.x) * Bw + bflo(q10.x) * Cw + bflo(q11.x) * Dw;
        float s1 = bfhi(q00.x) * A + bfhi(q01.x) * Bw + bfhi(q10.x) * Cw + bfhi(q11.x) * Dw;
        float s2 = bflo(q00.y) * A + bflo(q01.y) * Bw + bflo(q10.y) * Cw + bflo(q11.y) * Dw;
        float s3 = bfhi(q00.y) * A + bfhi(q01.y) * Bw + bfhi(q10.y) * Cw + bfhi(q11.y) * Dw;
        *(uint2*)(&smp[p][k * 64 + cq * 4]) = make_uint2(
            (unsigned)f2bf(s0) | ((unsigned)f2bf(s1) << 16),
            (unsigned)f2bf(s2) | ((unsigned)f2bf(s3) << 16));
    }
    __syncthreads();

    floatx4 acc = {0.f, 0.f, 0.f, 0.f};
    const unsigned short* bbase = &smp[r16][g * 8];
#pragma unroll
    for (int kk = 0; kk < 18; ++kk) {
        short8 bb = *(const short8*)(bbase + kk * 32);
        acc = __builtin_amdgcn_mfma_f32_16x16x32_bf16(a[kk], bb, acc, 0, 0, 0);
    }

    size_t obase = ((size_t)(b * Cch + wv * 16 + g * 4)) << 14;
    int hw = (h << 7) + w0 + r16;
#pragma unroll
    for (int r = 0; r < 4; ++r)
        out[obase + ((size_t)r << 14) + hw] = acc[r];
}

// ---------------------------------------------------------------------------
extern "C" void kernel_launch(void* const* d_in, const int* in_sizes, int n_in,
                              void* d_out, int out_size, void* d_ws, size_t ws_size,
                              hipStream_t stream) {
    const float* x      = (const float*)d_in[0];
    const float* ref    = (const float*)d_in[1];
    const float* wo     = (const float*)d_in[2];
    const float* bias   = (const float*)d_in[3];
    const float* weight = (const float*)d_in[4];
    float* out = (float*)d_out;

    unsigned short* w9  = (unsigned short*)d_ws;                      // 72 KB
    unsigned short* wbf = (unsigned short*)((char*)d_ws + 131072);    // 72 KB
    float* offs         = (float*)((char*)d_ws + 262144);             // 4.5 MB
    unsigned short* xtr = (unsigned short*)((char*)d_ws + 4980736);   // 8.4 MB

    hipLaunchKernelGGL(convert_w, dim3((Cch * CK + 255) / 256), dim3(256), 0, stream,
                       weight, wbf);
    hipLaunchKernelGGL(convert_w9, dim3((9 * 32 * 128 + 255) / 256), dim3(256), 0, stream,
                       wo, w9);
    hipLaunchKernelGGL(transpose_x, dim3(Bsz * 256), dim3(256), 0, stream, x, xtr);
    hipLaunchKernelGGL(offset_mfma, dim3(Bsz * Hh * (Ww / 16)), dim3(256), 0, stream,
                       x, ref, w9, bias, offs);
    hipLaunchKernelGGL(deform_mfma, dim3(Bsz * Hh * (Ww / 16)), dim3(256), 0, stream,
                       xtr, wbf, offs, out);
}

// Round 9
// 99.706 us; speedup vs baseline: 1.2251x; 1.2251x over previous
//
#include <hip/hip_runtime.h>

#define Bsz 4
#define Cch 64
#define Hh 128
#define Ww 128
#define NOFF 18      // 2*3*3 offset channels
#define CK 576       // 64*9 reduction length for deform einsum (K = k*64 + c)
#define CKPAD 580    // smp row stride (bf16): 1160B -> conflict-free r/w patterns

typedef __attribute__((ext_vector_type(8))) short short8;
typedef __attribute__((ext_vector_type(4))) float floatx4;

__device__ __forceinline__ unsigned short f2bf(float f) {
    union { float f; unsigned u; } v; v.f = f;
    unsigned r = v.u + 0x7fff + ((v.u >> 16) & 1);   // round-to-nearest-even
    return (unsigned short)(r >> 16);
}
__device__ __forceinline__ float bflo(unsigned d) {
    union { unsigned u; float f; } v; v.u = d << 16; return v.f;
}
__device__ __forceinline__ float bfhi(unsigned d) {
    union { unsigned u; float f; } v; v.u = d & 0xffff0000u; return v.f;
}

// ---------------------------------------------------------------------------
// Prep kernel.
//   blocks 0..1023   : transpose x||ref (NCHW f32) -> xtrc[b][h*w][128] bf16
//   blocks 1024..1167: deform weight w[oc][c][tap] -> wbf[oc][tap*64+c] bf16
//   blocks 1168..1311: offset weight wo[oc][ci][tap] -> w9[tap][32ocp][128ci] bf16
__global__ __launch_bounds__(256) void prep(const float* __restrict__ x,
                                            const float* __restrict__ ref,
                                            const float* __restrict__ wo,
                                            const float* __restrict__ w,
                                            unsigned short* __restrict__ xtrc,
                                            unsigned short* __restrict__ w9,
                                            unsigned short* __restrict__ wbf) {
    __shared__ unsigned tile[64][66];   // [cpair][px], +2 pad
    int bid = blockIdx.x;
    int tid = threadIdx.x;
    if (bid < 1024) {
        int b = bid >> 8;
        int hw0 = (bid & 255) << 6;
        int px = tid & 63, cg = tid >> 6;
        const float* xb = x + ((size_t)b << 20) + hw0 + px;
        const float* rb = ref + ((size_t)b << 20) + hw0 + px;
#pragma unroll
        for (int i = 0; i < 16; ++i) {
            int cpair = cg * 16 + i;        // c = 2*cpair, 2*cpair+1
            int c0 = cpair << 1;
            const float* s = (c0 < 64) ? xb : rb;
            int cl = c0 & 63;
            float v0 = s[(size_t)cl << 14];
            float v1 = s[(size_t)(cl + 1) << 14];
            tile[cpair][px] = (unsigned)f2bf(v0) | ((unsigned)f2bf(v1) << 16);
        }
        __syncthreads();
        int p2 = tid >> 4, cq = tid & 15;
#pragma unroll
        for (int j = 0; j < 4; ++j) {
            int px2 = (j << 4) + p2;
            unsigned short* orow = xtrc + (((size_t)(b << 14) + hw0 + px2) << 7);
#pragma unroll
            for (int jj = 0; jj < 2; ++jj) {
                unsigned v0 = tile[(cq << 1) + (jj << 5)][px2];
                unsigned v1 = tile[(cq << 1) + 1 + (jj << 5)][px2];
                *(uint2*)(orow + (cq << 2) + (jj << 6)) = make_uint2(v0, v1);
            }
        }
    } else if (bid < 1168) {
        int t = (bid - 1024) * 256 + tid;
        if (t < Cch * CK) {
            int oc = t / CK;
            int rem = t % CK;
            int k = rem >> 6, c = rem & 63;
            wbf[t] = f2bf(w[(oc * Cch + c) * 9 + k]);
        }
    } else {
        int t = (bid - 1168) * 256 + tid;
        if (t < 9 * 32 * 128) {
            int ci = t & 127, ocp = (t >> 7) & 31, tap = t >> 12;
            w9[t] = (ocp < NOFF) ? f2bf(wo[(ocp * 128 + ci) * 9 + tap]) : (unsigned short)0;
        }
    }
}

// ---------------------------------------------------------------------------
// Fused kernel: offset conv (MFMA) + deformable conv (MFMA) per 16-px strip.
// Phase A0: stage tile3[3row][18col][128ci] bf16 from xtrc, coalesced,
//           ci XOR-swizzled by (xx&7)<<3 (conflict-free column reads).
// Phase A1: 9 tap-shifted MFMAs -> offsets -> clip -> offsL LDS (no HBM).
// Phase B : bilinear gather from xtrc (coalesced channel-runs) -> smp LDS.
// Phase B1: 18 MFMAs -> out.
__global__ __launch_bounds__(256, 4) void fused_align(
        const unsigned short* __restrict__ xtrc,
        const unsigned short* __restrict__ w9,
        const unsigned short* __restrict__ wbf,
        const float* __restrict__ bias,
        float* __restrict__ out) {
    __shared__ union {
        struct { unsigned short tile3[54 * 128]; float red[2][64][4]; } A;   // 15.9 KB
        unsigned short smp[16][CKPAD];                                        // 18.6 KB
    } u;
    __shared__ float offsL[16][20];

    int bi = blockIdx.x;
    int b = bi >> 10;
    int rem = bi & 1023;
    int h = rem >> 3;
    int w0 = (rem & 7) << 4;
    int tid = threadIdx.x;
    int wv = tid >> 6, lane = tid & 63;
    int to = wv & 1;          // oc tile (offset conv)
    int kh = wv >> 1;         // ci half (offset conv)
    int r16 = lane & 15;
    int g = lane >> 4;

    const unsigned short* xrow = xtrc + ((size_t)b << 21);   // b * 16384 * 128

    // ---- Phase A0: stage 54 positions x 256B, fully coalesced ----
#pragma unroll
    for (int it = 0; it < 7; ++it) {
        int idx = it * 256 + tid;
        if (idx < 1728) {
            int lane32 = idx & 31;
            int pos = idx >> 5;              // row*18 + xx
            int row = pos / 18, xx = pos % 18;
            int yy = h + row - 1, xg = w0 + xx - 1;
            uint2 v = make_uint2(0u, 0u);
            if ((unsigned)yy < (unsigned)Hh && (unsigned)xg < (unsigned)Ww)
                v = *(const uint2*)(xrow + ((((yy << 7) + xg) << 7) + (lane32 << 2)));
            int ci0 = lane32 << 2;
            *(uint2*)(&u.A.tile3[(pos << 7) + (ci0 ^ ((xx & 7) << 3))]) = v;
        }
    }
    __syncthreads();

    // ---- Phase A1: offset conv MFMA (9 taps x 2) ----
    floatx4 acc = {0.f, 0.f, 0.f, 0.f};
#pragma unroll
    for (int tap = 0; tap < 9; ++tap) {
        int dy = tap / 3, dx = tap % 3;
        int xxr = r16 + dx;                              // 0..17
        const unsigned short* brow = &u.A.tile3[(dy * 18 + xxr) << 7];
        int sw = (xxr & 7) << 3;
        const unsigned short* arow = w9 + ((size_t)(tap * 32 + to * 16 + r16) << 7) + kh * 64;
#pragma unroll
        for (int kk = 0; kk < 2; ++kk) {
            int cb = kh * 64 + kk * 32 + g * 8;
            short8 bb = *(const short8*)(brow + (cb ^ sw));
            short8 a = *(const short8*)(arow + kk * 32 + g * 8);
            acc = __builtin_amdgcn_mfma_f32_16x16x32_bf16(a, bb, acc, 0, 0, 0);
        }
    }
    if (kh == 1) {
#pragma unroll
        for (int r = 0; r < 4; ++r) u.A.red[to][lane][r] = acc[r];
    }
    __syncthreads();
    if (kh == 0) {
#pragma unroll
        for (int r = 0; r < 4; ++r) {
            int oc = to * 16 + g * 4 + r;
            if (oc < NOFF) {
                float v = acc[r] + u.A.red[to][lane][r] + bias[oc];
                v = fminf(fmaxf(v, -10.0f), 10.0f);
                offsL[r16][oc] = v;
            }
        }
    }
    __syncthreads();   // offsL ready; tile3/red dead -> smp may overwrite

    // ---- Phase B: bilinear gather from xtrc ----
    {
        int p = tid >> 4;          // pixel (16 lanes share -> broadcast offsL)
        int cq = tid & 15;         // channel quad
        const unsigned short* xb = xrow + (cq << 2);
#pragma unroll
        for (int k = 0; k < 9; ++k) {
            int ky = k / 3, kx = k % 3;
            float2 o = *(const float2*)(&offsL[p][2 * k]);
            float ys = (float)(h - 1 + ky) + o.x;
            float xs = (float)(w0 + p - 1 + kx) + o.y;
            float fy = floorf(ys), fx = floorf(xs);
            int iy0 = (int)fy, ix0 = (int)fx;
            float ty = ys - fy, tx = xs - fx;
            float wy0 = (1.f - ty) * (((unsigned)iy0 < (unsigned)Hh) ? 1.f : 0.f);
            float wy1 = ty         * (((unsigned)(iy0 + 1) < (unsigned)Hh) ? 1.f : 0.f);
            float wx0 = (1.f - tx) * (((unsigned)ix0 < (unsigned)Ww) ? 1.f : 0.f);
            float wx1 = tx         * (((unsigned)(ix0 + 1) < (unsigned)Ww) ? 1.f : 0.f);
            int ixb  = min(max(ix0, 0), Ww - 2);          // pair base [ixb, ixb+1]
            int iy0c = min(max(iy0, 0), Hh - 1);
            int iy1c = min(max(iy0 + 1, 0), Hh - 1);
            bool sw0 = (min(max(ix0, 0), Ww - 1) != ixb);
            bool sw1 = (min(max(ix0 + 1, 0), Ww - 1) != ixb);
            float w00 = wy0 * wx0, w01 = wy0 * wx1, w10 = wy1 * wx0, w11 = wy1 * wx1;
            float A  = (sw0 ? 0.f : w00) + (sw1 ? 0.f : w01);   // (y0, ixb)
            float Bw = (sw0 ? w00 : 0.f) + (sw1 ? w01 : 0.f);   // (y0, ixb+1)
            float Cw = (sw0 ? 0.f : w10) + (sw1 ? 0.f : w11);   // (y1, ixb)
            float Dw = (sw0 ? w10 : 0.f) + (sw1 ? w11 : 0.f);   // (y1, ixb+1)
            int m0 = ((iy0c << 7) + ixb) << 7;   // u16 index: position * 128
            int m1 = ((iy1c << 7) + ixb) << 7;
            uint2 q00 = *(const uint2*)(xb + m0);
            uint2 q01 = *(const uint2*)(xb + m0 + 128);
            uint2 q10 = *(const uint2*)(xb + m1);
            uint2 q11 = *(const uint2*)(xb + m1 + 128);
            float s0 = bflo(q00.x) * A + bflo(q01.x) * Bw + bflo(q10.x) * Cw + bflo(q11.x) * Dw;
            float s1 = bfhi(q00.x) * A + bfhi(q01.x) * Bw + bfhi(q10.x) * Cw + bfhi(q11.x) * Dw;
            float s2 = bflo(q00.y) * A + bflo(q01.y) * Bw + bflo(q10.y) * Cw + bflo(q11.y) * Dw;
            float s3 = bfhi(q00.y) * A + bfhi(q01.y) * Bw + bfhi(q10.y) * Cw + bfhi(q11.y) * Dw;
            *(uint2*)(&u.smp[p][k * 64 + cq * 4]) = make_uint2(
                (unsigned)f2bf(s0) | ((unsigned)f2bf(s1) << 16),
                (unsigned)f2bf(s2) | ((unsigned)f2bf(s3) << 16));
        }
    }
    __syncthreads();

    // ---- Phase B1: deform MFMA (18) + store ----
    floatx4 acc2 = {0.f, 0.f, 0.f, 0.f};
    const short8* ap = (const short8*)(wbf + (size_t)(wv * 16 + r16) * CK + g * 8);
    const unsigned short* bbase = &u.smp[r16][g * 8];
#pragma unroll
    for (int kk = 0; kk < 18; ++kk) {
        short8 a = ap[kk * 4];
        short8 bb = *(const short8*)(bbase + kk * 32);
        acc2 = __builtin_amdgcn_mfma_f32_16x16x32_bf16(a, bb, acc2, 0, 0, 0);
    }
    size_t obase = ((size_t)(b * Cch + wv * 16 + g * 4)) << 14;
    int hw = (h << 7) + w0 + r16;
#pragma unroll
    for (int r = 0; r < 4; ++r)
        out[obase + ((size_t)r << 14) + hw] = acc2[r];
}

// ---------------------------------------------------------------------------
extern "C" void kernel_launch(void* const* d_in, const int* in_sizes, int n_in,
                              void* d_out, int out_size, void* d_ws, size_t ws_size,
                              hipStream_t stream) {
    const float* x      = (const float*)d_in[0];
    const float* ref    = (const float*)d_in[1];
    const float* wo     = (const float*)d_in[2];
    const float* bias   = (const float*)d_in[3];
    const float* weight = (const float*)d_in[4];
    float* out = (float*)d_out;

    unsigned short* w9   = (unsigned short*)d_ws;                      // 72 KB
    unsigned short* wbf  = (unsigned short*)((char*)d_ws + 131072);    // 72 KB
    unsigned short* xtrc = (unsigned short*)((char*)d_ws + 262144);    // 16.78 MB

    hipLaunchKernelGGL(prep, dim3(1312), dim3(256), 0, stream,
                       x, ref, wo, weight, xtrc, w9, wbf);
    hipLaunchKernelGGL(fused_align, dim3(Bsz * Hh * (Ww / 16)), dim3(256), 0, stream,
                       xtrc, w9, wbf, bias, out);
}